// Round 1
// baseline (407.440 us; speedup 1.0000x reference)
//
#include <hip/hip_runtime.h>

#define T_DIM 1024
#define B_DIM 64
#define H_DIM 1024
#define OSPLIT 4   // split the o-reduction of v = hidden@W into 4 partials

// ---------------------------------------------------------------------------
// Kernel 1: v_part[os][b][h] = sum_{o in chunk os} hidden[b][o] * W[o][h]
// grid (H/64, B/4, OSPLIT) = (16,16,4) = 1024 blocks, 64 threads.
// Each thread owns one h, accumulates 4 b's; hidden chunk staged in LDS
// (broadcast reads, conflict-free). W column reads coalesced across the wave.
// ---------------------------------------------------------------------------
__global__ __launch_bounds__(64) void gemv_hw(const float* __restrict__ hidden,
                                              const float* __restrict__ W,
                                              float* __restrict__ v_part) {
    __shared__ float hid_s[4 * 256];               // hidden[b0..b0+3][o0..o0+255], 4 KB
    const int tid = threadIdx.x;                   // 0..63
    const int h   = blockIdx.x * 64 + tid;
    const int b0  = blockIdx.y * 4;
    const int os  = blockIdx.z;
    const int o0  = os * 256;

    // stage 4x256 floats = 256 float4s with 64 threads
    for (int i = tid; i < 256; i += 64) {
        const int bi = i >> 6;                     // which b (64 float4 per b)
        const int o4 = i & 63;                     // float4 index within 256 floats
        reinterpret_cast<float4*>(hid_s)[i] =
            reinterpret_cast<const float4*>(hidden + (size_t)(b0 + bi) * H_DIM + o0)[o4];
    }
    __syncthreads();

    float acc0 = 0.f, acc1 = 0.f, acc2 = 0.f, acc3 = 0.f;
    const float* wcol = W + (size_t)o0 * H_DIM + h;    // W[o][h], stride H per o
#pragma unroll 4
    for (int o = 0; o < 256; ++o) {
        const float w = wcol[(size_t)o * H_DIM];
        acc0 += hid_s[0 * 256 + o] * w;
        acc1 += hid_s[1 * 256 + o] * w;
        acc2 += hid_s[2 * 256 + o] * w;
        acc3 += hid_s[3 * 256 + o] * w;
    }
    float* vp = v_part + (size_t)os * B_DIM * H_DIM;
    vp[(size_t)(b0 + 0) * H_DIM + h] = acc0;
    vp[(size_t)(b0 + 1) * H_DIM + h] = acc1;
    vp[(size_t)(b0 + 2) * H_DIM + h] = acc2;
    vp[(size_t)(b0 + 3) * H_DIM + h] = acc3;
}

// ---------------------------------------------------------------------------
// Kernel 2 (dominant): energies[b][t] = enc[t][b][:] . v[b][:]
// grid (T/4, B) = (256,64) = 16384 blocks, 256 threads (4 waves).
// Block stages v[b] (summing the 4 partials) into LDS once; each wave handles
// one t: 4x float4 coalesced enc loads per lane, wave shuffle reduction.
// ---------------------------------------------------------------------------
__global__ __launch_bounds__(256) void energies_k(const float* __restrict__ enc,
                                                  const float* __restrict__ v_part,
                                                  float* __restrict__ energies) {
    __shared__ float v_s[H_DIM];                   // 4 KB
    const int tid = threadIdx.x;                   // 0..255
    const int b   = blockIdx.y;
    const int t   = blockIdx.x * 4 + (tid >> 6);
    const int lane = tid & 63;

    {   // stage v[b] = sum of partials; 256 threads x 1 float4 = 1024 floats
        float4 s = make_float4(0.f, 0.f, 0.f, 0.f);
#pragma unroll
        for (int os = 0; os < OSPLIT; ++os) {
            const float4 p = reinterpret_cast<const float4*>(
                v_part + ((size_t)os * B_DIM + b) * H_DIM)[tid];
            s.x += p.x; s.y += p.y; s.z += p.z; s.w += p.w;
        }
        reinterpret_cast<float4*>(v_s)[tid] = s;
    }
    __syncthreads();

    const float4* erow = reinterpret_cast<const float4*>(
        enc + ((size_t)t * B_DIM + b) * H_DIM);
    const float4* vrow = reinterpret_cast<const float4*>(v_s);
    float p = 0.f;
#pragma unroll
    for (int j = 0; j < 4; ++j) {
        const float4 e = erow[j * 64 + lane];      // 64 lanes x 16B = 1 KB/instr
        const float4 v = vrow[j * 64 + lane];
        p += e.x * v.x + e.y * v.y + e.z * v.z + e.w * v.w;
    }
#pragma unroll
    for (int off = 32; off >= 1; off >>= 1) p += __shfl_down(p, off, 64);
    if (lane == 0) energies[(size_t)b * T_DIM + t] = p;
}

// ---------------------------------------------------------------------------
// Kernel 3: softmax over t per b. grid (B) = 64 blocks, 256 threads,
// 4 t's per thread via float4. Bias term dropped (softmax-invariant).
// ---------------------------------------------------------------------------
__global__ __launch_bounds__(256) void softmax_k(const float* __restrict__ energies,
                                                 float* __restrict__ out) {
    __shared__ float red[4];
    const int b    = blockIdx.x;
    const int tid  = threadIdx.x;
    const int lane = tid & 63;
    const int wave = tid >> 6;

    float4 e = reinterpret_cast<const float4*>(energies + (size_t)b * T_DIM)[tid];

    float m = fmaxf(fmaxf(e.x, e.y), fmaxf(e.z, e.w));
#pragma unroll
    for (int off = 32; off >= 1; off >>= 1) m = fmaxf(m, __shfl_xor(m, off, 64));
    if (lane == 0) red[wave] = m;
    __syncthreads();
    m = fmaxf(fmaxf(red[0], red[1]), fmaxf(red[2], red[3]));

    e.x = __expf(e.x - m); e.y = __expf(e.y - m);
    e.z = __expf(e.z - m); e.w = __expf(e.w - m);
    float s = e.x + e.y + e.z + e.w;
#pragma unroll
    for (int off = 32; off >= 1; off >>= 1) s += __shfl_xor(s, off, 64);
    __syncthreads();                               // red[] reuse barrier
    if (lane == 0) red[wave] = s;
    __syncthreads();
    s = red[0] + red[1] + red[2] + red[3];

    const float inv = 1.0f / s;
    const float4 o4 = make_float4(e.x * inv, e.y * inv, e.z * inv, e.w * inv);
    reinterpret_cast<float4*>(out + (size_t)b * T_DIM)[tid] = o4;
}

// ---------------------------------------------------------------------------
extern "C" void kernel_launch(void* const* d_in, const int* in_sizes, int n_in,
                              void* d_out, int out_size, void* d_ws, size_t ws_size,
                              hipStream_t stream) {
    (void)in_sizes; (void)n_in; (void)out_size; (void)ws_size;
    const float* hidden = (const float*)d_in[0];   // [1,B,H]
    const float* enc    = (const float*)d_in[1];   // [T,B,H]
    const float* W      = (const float*)d_in[2];   // [H,H]
    // d_in[3] = bias: provably cancelled by softmax (constant over t) -> unused

    float* v_part   = (float*)d_ws;                                    // 1 MB
    float* energies = (float*)((char*)d_ws +
                      (size_t)OSPLIT * B_DIM * H_DIM * sizeof(float)); // 256 KB
    float* out = (float*)d_out;

    gemv_hw  <<<dim3(H_DIM / 64, B_DIM / 4, OSPLIT), 64,  0, stream>>>(hidden, W, v_part);
    energies_k<<<dim3(T_DIM / 4, B_DIM),             256, 0, stream>>>(enc, v_part, energies);
    softmax_k<<<dim3(B_DIM),                         256, 0, stream>>>(energies, out);
}

// Round 3
// 361.096 us; speedup vs baseline: 1.1283x; 1.1283x over previous
//
#include <hip/hip_runtime.h>

#define T_DIM 1024
#define B_DIM 64
#define H_DIM 1024
#define OSPLIT 8       // o-reduction split for v = hidden@W

// native clang vector type -> __builtin_nontemporal_load accepts it
typedef float floatx4 __attribute__((ext_vector_type(4)));

// nontemporal float4 load (enc is a read-once 268 MB stream)
__device__ __forceinline__ float4 ldnt4(const float* p) {
    floatx4 r = __builtin_nontemporal_load(reinterpret_cast<const floatx4*>(p));
    return make_float4(r.x, r.y, r.z, r.w);
}

// ---------------------------------------------------------------------------
// Kernel 1: v_part[os][b][h] = sum_{o in chunk} hidden[b][o] * W[o][h]
// grid (H/64, B/32, OSPLIT) = (16,2,8) = 256 blocks, 256 threads (4 waves).
// Wave w handles b in [y*32 + 8w, +8): 8 fp32 accs/thread, thread owns one h.
// hidden chunk in LDS (same-address broadcast reads -> conflict-free).
// W row reads coalesced (64 lanes x 4B); all 4 waves share the W chunk -> L1.
// W HBM fetch ~= 8 MB (was 64 MB); serial depth 128 (was 256).
// ---------------------------------------------------------------------------
__global__ __launch_bounds__(256) void gemv_hw(const float* __restrict__ hidden,
                                               const float* __restrict__ W,
                                               float* __restrict__ v_part) {
    __shared__ float hid_s[32 * 128];              // 16 KB: [bi][o]
    const int tid  = threadIdx.x;                  // 0..255
    const int lane = tid & 63;
    const int wv   = tid >> 6;                     // 0..3
    const int h    = blockIdx.x * 64 + lane;
    const int b0   = blockIdx.y * 32;
    const int o0   = blockIdx.z * 128;

    // stage hidden[b0..b0+31][o0..o0+127]: 1024 float4s, 4 per thread
#pragma unroll
    for (int r = 0; r < 4; ++r) {
        const int i  = tid + 256 * r;
        const int bi = i >> 5;                     // 32 float4 per b-row
        const int o4 = i & 31;
        reinterpret_cast<float4*>(hid_s)[i] =
            reinterpret_cast<const float4*>(hidden + (size_t)(b0 + bi) * H_DIM + o0)[o4];
    }
    __syncthreads();

    float acc[8];
#pragma unroll
    for (int j = 0; j < 8; ++j) acc[j] = 0.f;

    const float* wcol = W + (size_t)o0 * H_DIM + h;
    const float* hrow = hid_s + (wv * 8) * 128;    // this wave's 8 b-rows
#pragma unroll 4
    for (int o = 0; o < 128; ++o) {
        const float w = wcol[(size_t)o * H_DIM];
#pragma unroll
        for (int j = 0; j < 8; ++j) acc[j] += hrow[j * 128 + o] * w;
    }

    float* vp = v_part + ((size_t)blockIdx.z * B_DIM + b0 + wv * 8) * H_DIM + h;
#pragma unroll
    for (int j = 0; j < 8; ++j) vp[(size_t)j * H_DIM] = acc[j];
}

// ---------------------------------------------------------------------------
// Kernel 1b: v[b][h] = sum_os v_part[os][b][h]. 2 MB read, 256 KB write.
// grid 64 x 256 threads, one float4 per thread.
// ---------------------------------------------------------------------------
__global__ __launch_bounds__(256) void reduce_v(const float* __restrict__ v_part,
                                                float* __restrict__ v) {
    const int i = blockIdx.x * 256 + threadIdx.x;  // float4 index into [B*H/4)
    float4 s = make_float4(0.f, 0.f, 0.f, 0.f);
#pragma unroll
    for (int os = 0; os < OSPLIT; ++os) {
        const float4 p = reinterpret_cast<const float4*>(
            v_part + (size_t)os * B_DIM * H_DIM)[i];
        s.x += p.x; s.y += p.y; s.z += p.z; s.w += p.w;
    }
    reinterpret_cast<float4*>(v)[i] = s;
}

// ---------------------------------------------------------------------------
// Kernel 2 (dominant, HBM-bound): energies[b][t] = enc[t][b][:] . v[b][:]
// grid (T/16, B) = (64,64) = 4096 blocks, 256 threads (4 waves).
// Block stages v[b] (4 KB) once, amortized over 16 t-rows (was 4).
// Wave w handles t = x*16 + 4w + j, j<4: 16 independent nontemporal float4
// loads per lane in flight; shuffle-reduce per row.
// ---------------------------------------------------------------------------
__global__ __launch_bounds__(256) void energies_k(const float* __restrict__ enc,
                                                  const float* __restrict__ v,
                                                  float* __restrict__ energies) {
    __shared__ float v_s[H_DIM];                   // 4 KB
    const int tid  = threadIdx.x;
    const int lane = tid & 63;
    const int wv   = tid >> 6;
    const int b    = blockIdx.y;
    const int t0   = blockIdx.x * 16 + wv * 4;

    reinterpret_cast<float4*>(v_s)[tid] =
        reinterpret_cast<const float4*>(v + (size_t)b * H_DIM)[tid];
    __syncthreads();

    const float4* vrow = reinterpret_cast<const float4*>(v_s);
    float4 vk[4];
#pragma unroll
    for (int k = 0; k < 4; ++k) vk[k] = vrow[k * 64 + lane];

    float p[4];
#pragma unroll
    for (int j = 0; j < 4; ++j) {
        const float* erow = enc + ((size_t)(t0 + j) * B_DIM + b) * H_DIM;
        float acc = 0.f;
#pragma unroll
        for (int k = 0; k < 4; ++k) {
            const float4 e = ldnt4(erow + (k * 64 + lane) * 4);
            acc += e.x * vk[k].x + e.y * vk[k].y + e.z * vk[k].z + e.w * vk[k].w;
        }
        p[j] = acc;
    }
#pragma unroll
    for (int j = 0; j < 4; ++j) {
#pragma unroll
        for (int off = 32; off >= 1; off >>= 1) p[j] += __shfl_down(p[j], off, 64);
        if (lane == 0) energies[(size_t)b * T_DIM + t0 + j] = p[j];
    }
}

// ---------------------------------------------------------------------------
// Kernel 3: softmax over t per b. Bias dropped (constant over t -> cancels).
// ---------------------------------------------------------------------------
__global__ __launch_bounds__(256) void softmax_k(const float* __restrict__ energies,
                                                 float* __restrict__ out) {
    __shared__ float red[4];
    const int b    = blockIdx.x;
    const int tid  = threadIdx.x;
    const int lane = tid & 63;
    const int wave = tid >> 6;

    float4 e = reinterpret_cast<const float4*>(energies + (size_t)b * T_DIM)[tid];

    float m = fmaxf(fmaxf(e.x, e.y), fmaxf(e.z, e.w));
#pragma unroll
    for (int off = 32; off >= 1; off >>= 1) m = fmaxf(m, __shfl_xor(m, off, 64));
    if (lane == 0) red[wave] = m;
    __syncthreads();
    m = fmaxf(fmaxf(red[0], red[1]), fmaxf(red[2], red[3]));

    e.x = __expf(e.x - m); e.y = __expf(e.y - m);
    e.z = __expf(e.z - m); e.w = __expf(e.w - m);
    float s = e.x + e.y + e.z + e.w;
#pragma unroll
    for (int off = 32; off >= 1; off >>= 1) s += __shfl_xor(s, off, 64);
    __syncthreads();
    if (lane == 0) red[wave] = s;
    __syncthreads();
    s = red[0] + red[1] + red[2] + red[3];

    const float inv = 1.0f / s;
    const float4 o4 = make_float4(e.x * inv, e.y * inv, e.z * inv, e.w * inv);
    reinterpret_cast<float4*>(out + (size_t)b * T_DIM)[tid] = o4;
}

// ---------------------------------------------------------------------------
extern "C" void kernel_launch(void* const* d_in, const int* in_sizes, int n_in,
                              void* d_out, int out_size, void* d_ws, size_t ws_size,
                              hipStream_t stream) {
    (void)in_sizes; (void)n_in; (void)out_size; (void)ws_size;
    const float* hidden = (const float*)d_in[0];   // [1,B,H]
    const float* enc    = (const float*)d_in[1];   // [T,B,H]
    const float* W      = (const float*)d_in[2];   // [H,H]
    // d_in[3] = bias: constant over t -> cancelled by softmax, unused.

    float* v_part   = (float*)d_ws;                                       // 2 MB
    float* v        = v_part + (size_t)OSPLIT * B_DIM * H_DIM;            // 256 KB
    float* energies = v + (size_t)B_DIM * H_DIM;                          // 256 KB
    float* out = (float*)d_out;

    gemv_hw   <<<dim3(H_DIM / 64, B_DIM / 32, OSPLIT), 256, 0, stream>>>(hidden, W, v_part);
    reduce_v  <<<dim3(B_DIM * H_DIM / 4 / 256),        256, 0, stream>>>(v_part, v);
    energies_k<<<dim3(T_DIM / 16, B_DIM),              256, 0, stream>>>(enc, v, energies);
    softmax_k <<<dim3(B_DIM),                          256, 0, stream>>>(energies, out);
}

// Round 4
// 354.792 us; speedup vs baseline: 1.1484x; 1.0178x over previous
//
#include <hip/hip_runtime.h>

#define T_DIM 1024
#define B_DIM 64
#define H_DIM 1024
#define OSPLIT 16      // o-reduction split for v = hidden@W (512 blocks, depth 64)

// native clang vector type -> __builtin_nontemporal_load accepts it
typedef float floatx4 __attribute__((ext_vector_type(4)));

// nontemporal float4 load (enc is a read-once 268 MB stream)
__device__ __forceinline__ float4 ldnt4(const float* p) {
    floatx4 r = __builtin_nontemporal_load(reinterpret_cast<const floatx4*>(p));
    return make_float4(r.x, r.y, r.z, r.w);
}

// ---------------------------------------------------------------------------
// Kernel 1: v_part[os][b][h] = sum_{o in chunk} hidden[b][o] * W[o][h]
// grid (H/64, B/32, OSPLIT) = (16,2,16) = 512 blocks, 256 threads (4 waves).
// Wave w handles b in [y*32 + 8w, +8): 8 fp32 accs/thread, thread owns one h.
// hidden chunk in LDS (same-address broadcast reads -> conflict-free).
// W row reads coalesced (64 lanes x 4B); serial depth 64 strided loads.
// ---------------------------------------------------------------------------
__global__ __launch_bounds__(256) void gemv_hw(const float* __restrict__ hidden,
                                               const float* __restrict__ W,
                                               float* __restrict__ v_part) {
    __shared__ float hid_s[32 * 64];               // 8 KB: [bi][o]
    const int tid  = threadIdx.x;                  // 0..255
    const int lane = tid & 63;
    const int wv   = tid >> 6;                     // 0..3
    const int h    = blockIdx.x * 64 + lane;
    const int b0   = blockIdx.y * 32;
    const int o0   = blockIdx.z * 64;

    // stage hidden[b0..b0+31][o0..o0+63]: 512 float4s, 2 per thread
#pragma unroll
    for (int r = 0; r < 2; ++r) {
        const int i  = tid + 256 * r;
        const int bi = i >> 4;                     // 16 float4 per b-row
        const int o4 = i & 15;
        reinterpret_cast<float4*>(hid_s)[i] =
            reinterpret_cast<const float4*>(hidden + (size_t)(b0 + bi) * H_DIM + o0)[o4];
    }
    __syncthreads();

    float acc[8];
#pragma unroll
    for (int j = 0; j < 8; ++j) acc[j] = 0.f;

    const float* wcol = W + (size_t)o0 * H_DIM + h;
    const float* hrow = hid_s + (wv * 8) * 64;     // this wave's 8 b-rows
#pragma unroll 4
    for (int o = 0; o < 64; ++o) {
        const float w = wcol[(size_t)o * H_DIM];
#pragma unroll
        for (int j = 0; j < 8; ++j) acc[j] += hrow[j * 64 + o] * w;
    }

    float* vp = v_part + ((size_t)blockIdx.z * B_DIM + b0 + wv * 8) * H_DIM + h;
#pragma unroll
    for (int j = 0; j < 8; ++j) vp[(size_t)j * H_DIM] = acc[j];
}

// ---------------------------------------------------------------------------
// Kernel 1b: v[b][h] = sum_os v_part[os][b][h]. 4 MB read (L2), 256 KB write.
// grid 64 x 256 threads, one float4 per thread.
// ---------------------------------------------------------------------------
__global__ __launch_bounds__(256) void reduce_v(const float* __restrict__ v_part,
                                                float* __restrict__ v) {
    const int i = blockIdx.x * 256 + threadIdx.x;  // float4 index into [B*H/4)
    float4 s = make_float4(0.f, 0.f, 0.f, 0.f);
#pragma unroll
    for (int os = 0; os < OSPLIT; ++os) {
        const float4 p = reinterpret_cast<const float4*>(
            v_part + (size_t)os * B_DIM * H_DIM)[i];
        s.x += p.x; s.y += p.y; s.z += p.z; s.w += p.w;
    }
    reinterpret_cast<float4*>(v)[i] = s;
}

// ---------------------------------------------------------------------------
// Kernel 2 (dominant, HBM-bound): energies[b][t] = enc[t][b][:] . v[b][:]
// grid (T/16, B) = (64,64) = 4096 blocks, 256 threads (4 waves).
// Block stages v[b] (4 KB) once, amortized over 16 t-rows.
// Wave w handles t = x*16 + 4w + j, j<4: 16 independent nontemporal float4
// loads per lane in flight; shuffle-reduce per row.
// ---------------------------------------------------------------------------
__global__ __launch_bounds__(256) void energies_k(const float* __restrict__ enc,
                                                  const float* __restrict__ v,
                                                  float* __restrict__ energies) {
    __shared__ float v_s[H_DIM];                   // 4 KB
    const int tid  = threadIdx.x;
    const int lane = tid & 63;
    const int wv   = tid >> 6;
    const int b    = blockIdx.y;
    const int t0   = blockIdx.x * 16 + wv * 4;

    reinterpret_cast<float4*>(v_s)[tid] =
        reinterpret_cast<const float4*>(v + (size_t)b * H_DIM)[tid];
    __syncthreads();

    const float4* vrow = reinterpret_cast<const float4*>(v_s);
    float4 vk[4];
#pragma unroll
    for (int k = 0; k < 4; ++k) vk[k] = vrow[k * 64 + lane];

    float p[4];
#pragma unroll
    for (int j = 0; j < 4; ++j) {
        const float* erow = enc + ((size_t)(t0 + j) * B_DIM + b) * H_DIM;
        float acc = 0.f;
#pragma unroll
        for (int k = 0; k < 4; ++k) {
            const float4 e = ldnt4(erow + (k * 64 + lane) * 4);
            acc += e.x * vk[k].x + e.y * vk[k].y + e.z * vk[k].z + e.w * vk[k].w;
        }
        p[j] = acc;
    }
#pragma unroll
    for (int j = 0; j < 4; ++j) {
#pragma unroll
        for (int off = 32; off >= 1; off >>= 1) p[j] += __shfl_down(p[j], off, 64);
        if (lane == 0) energies[(size_t)b * T_DIM + t0 + j] = p[j];
    }
}

// ---------------------------------------------------------------------------
// Kernel 3: softmax over t per b. Bias dropped (constant over t -> cancels).
// ---------------------------------------------------------------------------
__global__ __launch_bounds__(256) void softmax_k(const float* __restrict__ energies,
                                                 float* __restrict__ out) {
    __shared__ float red[4];
    const int b    = blockIdx.x;
    const int tid  = threadIdx.x;
    const int lane = tid & 63;
    const int wave = tid >> 6;

    float4 e = reinterpret_cast<const float4*>(energies + (size_t)b * T_DIM)[tid];

    float m = fmaxf(fmaxf(e.x, e.y), fmaxf(e.z, e.w));
#pragma unroll
    for (int off = 32; off >= 1; off >>= 1) m = fmaxf(m, __shfl_xor(m, off, 64));
    if (lane == 0) red[wave] = m;
    __syncthreads();
    m = fmaxf(fmaxf(red[0], red[1]), fmaxf(red[2], red[3]));

    e.x = __expf(e.x - m); e.y = __expf(e.y - m);
    e.z = __expf(e.z - m); e.w = __expf(e.w - m);
    float s = e.x + e.y + e.z + e.w;
#pragma unroll
    for (int off = 32; off >= 1; off >>= 1) s += __shfl_xor(s, off, 64);
    __syncthreads();
    if (lane == 0) red[wave] = s;
    __syncthreads();
    s = red[0] + red[1] + red[2] + red[3];

    const float inv = 1.0f / s;
    const float4 o4 = make_float4(e.x * inv, e.y * inv, e.z * inv, e.w * inv);
    reinterpret_cast<float4*>(out + (size_t)b * T_DIM)[tid] = o4;
}

// ---------------------------------------------------------------------------
extern "C" void kernel_launch(void* const* d_in, const int* in_sizes, int n_in,
                              void* d_out, int out_size, void* d_ws, size_t ws_size,
                              hipStream_t stream) {
    (void)in_sizes; (void)n_in; (void)out_size; (void)ws_size;
    const float* hidden = (const float*)d_in[0];   // [1,B,H]
    const float* enc    = (const float*)d_in[1];   // [T,B,H]
    const float* W      = (const float*)d_in[2];   // [H,H]
    // d_in[3] = bias: constant over t -> cancelled by softmax, unused.

    float* v_part   = (float*)d_ws;                                       // 4 MB
    float* v        = v_part + (size_t)OSPLIT * B_DIM * H_DIM;            // 256 KB
    float* energies = v + (size_t)B_DIM * H_DIM;                          // 256 KB
    float* out = (float*)d_out;

    gemv_hw   <<<dim3(H_DIM / 64, B_DIM / 32, OSPLIT), 256, 0, stream>>>(hidden, W, v_part);
    reduce_v  <<<dim3(B_DIM * H_DIM / 4 / 256),        256, 0, stream>>>(v_part, v);
    energies_k<<<dim3(T_DIM / 16, B_DIM),              256, 0, stream>>>(enc, v, energies);
    softmax_k <<<dim3(B_DIM),                          256, 0, stream>>>(energies, out);
}